// Round 16
// baseline (39.565 us; speedup 1.0000x reference)
//
#include <hip/hip_runtime.h>

// VQ-VAE codebook: z [32,64,32,32] f32 NCHW, embedding [1024,64] f32.
// Outputs (concat, f32): z_q NCHW (2097152) | indices as float (32768) | loss (1).
//
// R16: occupancy was structurally capped at 2 waves/SIMD (2048 waves total).
// k-split waves (16 rows x 512 codes) -> 4096 waves; 16 KB dbuf tiles keep
// LDS ~38 KB -> 4 blocks/CU resident. MFMA chain split 3x2. Screen keys:
// u32 with 5-bit group-local id (perturb ~1e-3); per-half top-2; full-k
// reconstructed at extraction (u64 shuffle reduce, once). 4 candidates/row
// exact-fp32 re-verified in-kernel (R14-proven); ties -> smallest k.

#define IDX_OFF 2097152
#define LOSS_OFF 2129920
#define BIGF 160.0f
#define RL 72
#define U32INF 0xFFFFFFFFu
#define U64INF 0xFFFFFFFFFFFFFFFFull

typedef __attribute__((ext_vector_type(8))) short bf16x8;
typedef __attribute__((ext_vector_type(4))) float f32x4;

__device__ __align__(256) float g_ep[1024 * RL];     // [-2e | ||e||^2+160 | pad]
__device__ __align__(256) float g_enb[1024];         // dense ||e||^2+160
__device__ __align__(256) unsigned short g_bf[64 * 4 * 64 * 8]; // [g][f][lane][j]
__device__ float g_partial[1024];

typedef const __attribute__((address_space(1))) void* gvp;
typedef __attribute__((address_space(3))) void* lvp;

__device__ __forceinline__ void gll16(const void* g, void* l) {
    __builtin_amdgcn_global_load_lds((gvp)g, (lvp)l, 16, 0, 0);
}

__device__ __forceinline__ unsigned int f2bf(float f) {   // fp32 -> bf16, RTN-even
    unsigned int u = __float_as_uint(f);
    return (u + 0x7FFFu + ((u >> 16) & 1u)) >> 16;
}

__device__ __forceinline__ unsigned long long min16u64(unsigned long long x) {
#pragma unroll
    for (int o = 1; o < 16; o <<= 1) {
        unsigned long long y = __shfl_xor(x, o, 64);
        x = y < x ? y : x;
    }
    return x;
}

// ---------------- kernel 0: build e', enb, packed B-frags ------------------
// B-frag layout (R11-verified): group g, lane l (col=l&15, g4=l>>4):
// f=0: bf16(-2e)[g*16+col][g4*8+j]  f=1: ...[32+g4*8+j]  f=2/3: lo-residual.
// g_bf[((g*4+f)*64+l)*8+j] -> linear DMA staging + conflict-free ds_read_b128.
__global__ __launch_bounds__(256) void vq_prep(const float* __restrict__ e) {
    int lane = threadIdx.x & 63;
    int k    = blockIdx.x * 4 + (threadIdx.x >> 6);
    float v  = e[k * 64 + lane];
    float m2 = -2.0f * v;
    float s  = v * v;
#pragma unroll
    for (int o = 32; o; o >>= 1) s += __shfl_xor(s, o, 64);
    g_ep[(size_t)k * RL + lane] = m2;
    if (lane == 0) { g_ep[(size_t)k * RL + 64] = s + BIGF; g_enb[k] = s + BIGF; }
    unsigned hb = f2bf(m2);
    float    hf = __uint_as_float(hb << 16);
    unsigned lb = f2bf(m2 - hf);
    int g  = k >> 4, c = k & 15;
    int ch = lane >> 5, dc = lane & 31;
    int g4 = dc >> 3,  j = dc & 7;
    int l  = g4 * 16 + c;
    g_bf[(size_t)((g * 4 + ch) * 64 + l) * 8 + j]     = (unsigned short)hb;
    g_bf[(size_t)((g * 4 + 2 + ch) * 64 + l) * 8 + j] = (unsigned short)lb;
}

// ---------------- kernel 1: fused screen + verify + epilogue ---------------
// grid 1024: 32 rows/block, 4 waves; wave w = (rh=w&1 row-half, kh=w>>1
// k-half). 16 tiles x (2 groups per half) = 16 KB tiles, dbuf. Per-lane
// top-2 u32 keys (5-bit gl). Verify: wave w = slot (kh=w>>1, sl=w&1).
__global__ __launch_bounds__(256, 4) void vq_main(const float* __restrict__ z,
                                                  const float* __restrict__ e,
                                                  float* __restrict__ out) {
    __shared__ unsigned short bf[2][8192];       // 2 x 16 KB
    __shared__ float enb[1024];                  // 4 KB
    __shared__ int   stop[2][32][2];             // cand k per (kh,row,slot)
    __shared__ unsigned long long skey[4][32];   // exact keys per slot
    __shared__ int   ishare[32];
    __shared__ float lred[4];

    const int t    = threadIdx.x;
    const int lane = t & 63;
    const int w    = __builtin_amdgcn_readfirstlane(t >> 6);  // 0..3
    const int col  = lane & 15;
    const int g4   = lane >> 4;
    const int rh   = w & 1;
    const int kh   = w >> 1;
    const int bid  = blockIdx.x;      // 0..1023
    const int b    = bid >> 5;
    const int hw0  = (bid & 31) << 5;

    // stage enb (4 KB, 1 seg/wave) + B-tile 0 (16 segs, 4/wave) via linear DMA
    gll16((const char*)g_enb + w * 1024 + lane * 16, (char*)enb + w * 1024);
#pragma unroll
    for (int i = 0; i < 4; ++i) {
        int s  = w * 4 + i;                       // seg: h=s>>3, ig=(s>>2)&1, f=s&3
        int h  = s >> 3, ig = (s >> 2) & 1, f = s & 3;
        gll16((const char*)g_bf + (size_t)(((h * 32 + ig) * 4 + f) * 1024) + lane * 16,
              (char*)&bf[0][0] + s * 1024 + lane * 16);
    }

    // A-fragments for this wave's 16 rows (computed -> VGPR-resident)
    const float* zr = z + (size_t)b * 65536 + hw0 + (rh * 16 + col);
    bf16x8 zh[2], zl[2];
#pragma unroll
    for (int c = 0; c < 2; ++c)
#pragma unroll
        for (int j = 0; j < 8; ++j) {
            int d = c * 32 + g4 * 8 + j;
            float f = zr[(size_t)d * 1024];
            unsigned hb = f2bf(f);
            float    hf = __uint_as_float(hb << 16);
            unsigned lb = f2bf(f - hf);
            zh[c][j] = (short)hb;
            zl[c][j] = (short)lb;
        }

    unsigned int t0[4], t1[4];
#pragma unroll
    for (int r = 0; r < 4; ++r) { t0[r] = U32INF; t1[r] = U32INF; }

    __syncthreads();   // DMA drained -> tile 0 + enb visible

    for (int tt = 0; tt < 16; ++tt) {
        const int cur = tt & 1;
        if (tt < 15) {   // prefetch next tile (fire-and-forget DMA)
#pragma unroll
            for (int i = 0; i < 4; ++i) {
                int s  = w * 4 + i;
                int h  = s >> 3, ig = (s >> 2) & 1, f = s & 3;
                gll16((const char*)g_bf +
                          (size_t)(((h * 32 + (tt + 1) * 2 + ig) * 4 + f) * 1024) + lane * 16,
                      (char*)&bf[cur ^ 1][0] + s * 1024 + lane * 16);
            }
        }

        const unsigned short* bfc = &bf[cur][0];
#pragma unroll
        for (int i = 0; i < 2; ++i) {
            const int gl = tt * 2 + i;            // group-local id in [0,32)
            const int kc = kh * 512 + gl * 16 + col;
            const bf16x8* p = (const bf16x8*)bfc + (kh * 2 + i) * 256;
            bf16x8 eh0 = p[lane];                 // contiguous ds_read_b128
            bf16x8 eh1 = p[64 + lane];
            bf16x8 el0 = p[128 + lane];
            bf16x8 el1 = p[192 + lane];

            // 3 independent 2-MFMA chains (halved latency exposure)
            f32x4 aa = {0.f, 0.f, 0.f, 0.f};
            f32x4 ab = {0.f, 0.f, 0.f, 0.f};
            f32x4 ac = {0.f, 0.f, 0.f, 0.f};
            aa = __builtin_amdgcn_mfma_f32_16x16x32_bf16(zh[0], eh0, aa, 0, 0, 0);
            ab = __builtin_amdgcn_mfma_f32_16x16x32_bf16(zh[0], el0, ab, 0, 0, 0);
            ac = __builtin_amdgcn_mfma_f32_16x16x32_bf16(zl[0], eh0, ac, 0, 0, 0);
            aa = __builtin_amdgcn_mfma_f32_16x16x32_bf16(zh[1], eh1, aa, 0, 0, 0);
            ab = __builtin_amdgcn_mfma_f32_16x16x32_bf16(zh[1], el1, ab, 0, 0, 0);
            ac = __builtin_amdgcn_mfma_f32_16x16x32_bf16(zl[1], eh1, ac, 0, 0, 0);

            float enbv = enb[kc];
#pragma unroll
            for (int r = 0; r < 4; ++r) {
                float cand = (aa[r] + ab[r]) + (ac[r] + enbv);  // >0 -> uint order ok
                unsigned int key = (__float_as_uint(cand) & ~31u) | (unsigned)gl;
                unsigned int a0 = t0[r] < key ? t0[r] : key;    // top-2 insert: 3 ops
                unsigned int x  = t0[r] < key ? key : t0[r];
                unsigned int a1 = t1[r] < x ? t1[r] : x;
                t0[r] = a0; t1[r] = a1;
            }
        }
        __syncthreads();   // readers done with bf[cur]; next DMA drained
    }

    // per (row, kh): expand to u64 with full k (lane knows col), top-2 extract
#pragma unroll
    for (int r = 0; r < 4; ++r) {
        unsigned long long ku0 =
            ((unsigned long long)(t0[r] & ~31u) << 32) |
            (unsigned)(kh * 512 + (int)(t0[r] & 31u) * 16 + col);
        unsigned long long ku1 =
            ((unsigned long long)(t1[r] & ~31u) << 32) |
            (unsigned)(kh * 512 + (int)(t1[r] & 31u) * 16 + col);
        unsigned long long m1 = min16u64(ku0);
        if (ku0 == m1) ku0 = ku1;               // keys unique within group of 16
        unsigned long long m2 = min16u64(ku0);
        int row = rh * 16 + g4 * 4 + r;          // row-in-block [0,32)
        if (col == 0) {
            stop[kh][row][0] = (int)(m1 & 1023u);
            stop[kh][row][1] = (int)(m2 & 1023u);
        }
    }
    __syncthreads();

    // ---- verify: wave w = slot (kh=w>>1, sl=w&1); lanes 0-31 = rows ----
    if (lane < 32) {
        int kc = stop[w >> 1][lane][w & 1];
        const float* zbase = z + (size_t)b * 65536 + hw0 + lane;   // L1/L2-hot
        const float* ep    = g_ep + (size_t)kc * RL;
        float d0 = 0.f, d1 = 0.f, d2 = 0.f, d3 = 0.f;
#pragma unroll
        for (int dq = 0; dq < 16; ++dq) {
            float4 ev = *(const float4*)(ep + dq * 4);
            d0 = fmaf(zbase[(size_t)(dq * 4 + 0) * 1024], ev.x, d0);
            d1 = fmaf(zbase[(size_t)(dq * 4 + 1) * 1024], ev.y, d1);
            d2 = fmaf(zbase[(size_t)(dq * 4 + 2) * 1024], ev.z, d2);
            d3 = fmaf(zbase[(size_t)(dq * 4 + 3) * 1024], ev.w, d3);
        }
        float dist = (d0 + d1) + (d2 + d3) + ep[64];
        skey[w][lane] = ((unsigned long long)__float_as_uint(dist) << 32) | (unsigned)kc;
    }
    __syncthreads();

    if (w == 0 && lane < 32) {
        unsigned long long ky = skey[0][lane];
        unsigned long long k1 = skey[1][lane];
        unsigned long long k2 = skey[2][lane];
        unsigned long long k3 = skey[3][lane];
        ky = k1 < ky ? k1 : ky;
        ky = k2 < ky ? k2 : ky;
        ky = k3 < ky ? k3 : ky;         // exact min; ties -> smallest k
        int idx = (int)(ky & 0xFFFFFFFFull);
        out[IDX_OFF + bid * 32 + lane] = (float)idx;
        ishare[lane] = idx;
    }
    __syncthreads();

    // ---- epilogue: z_q + loss partial. thread t: row r=t&31, d-block t>>5 --
    {
        int r  = t & 31;
        int dg = t >> 5;                 // 0..7 -> d = dg*8 .. dg*8+7
        int idx = ishare[r];
        const float*  zbase = z + (size_t)b * 65536 + hw0 + r;
        float*        qbase = out + (size_t)b * 65536 + hw0 + r;
        const float4* er4   = (const float4*)(e + (size_t)idx * 64) + dg * 2;

        float lsum = 0.f;
#pragma unroll
        for (int p = 0; p < 2; ++p) {
            float4 ev = er4[p];                    // gather, L1/L2-resident
            int d = dg * 8 + p * 4;
            float ezw[4] = {ev.x, ev.y, ev.z, ev.w};
#pragma unroll
            for (int qq = 0; qq < 4; ++qq) {
                float zv = zbase[(size_t)(d + qq) * 1024];
                float df = ezw[qq] - zv;
                lsum = fmaf(df, df, lsum);
                qbase[(size_t)(d + qq) * 1024] = ezw[qq];  // coalesced across r
            }
        }
#pragma unroll
        for (int o = 32; o; o >>= 1) lsum += __shfl_xor(lsum, o, 64);
        if (lane == 0) lred[w] = lsum;
    }
    __syncthreads();
    if (t == 0)
        g_partial[bid] = (lred[0] + lred[1]) + (lred[2] + lred[3]);
}

// ---------------- kernel 2: loss scalar ------------------------------------
__global__ __launch_bounds__(64) void vq_finish(float* __restrict__ out) {
    int lane = threadIdx.x;
    float s = 0.f;
#pragma unroll
    for (int i = 0; i < 16; ++i) s += g_partial[lane * 16 + i];
#pragma unroll
    for (int o = 32; o; o >>= 1) s += __shfl_xor(s, o, 64);
    // loss = q_latent + 0.25*e_latent = 1.25 * mean((z_q - z)^2)
    if (lane == 0) out[LOSS_OFF] = s * (1.25f / 2097152.0f);
}

extern "C" void kernel_launch(void* const* d_in, const int* in_sizes, int n_in,
                              void* d_out, int out_size, void* d_ws, size_t ws_size,
                              hipStream_t stream) {
    const float* z = (const float*)d_in[0];
    const float* e = (const float*)d_in[1];
    float* out = (float*)d_out;

    vq_prep<<<256, 256, 0, stream>>>(e);
    vq_main<<<1024, 256, 0, stream>>>(z, e, out);
    vq_finish<<<1, 64, 0, stream>>>(out);
}